// Round 8
// baseline (246.893 us; speedup 1.0000x reference)
//
#include <hip/hip_runtime.h>
#include <math.h>

#define HID 128
#define NHEAD 8
#define NL 3
#define NS 256
#define ROWS 4096

typedef __attribute__((ext_vector_type(8))) short bf16x8;
typedef __attribute__((ext_vector_type(4))) float f32x4;

__device__ __forceinline__ float us2f(unsigned short s) { return __uint_as_float(((unsigned)s) << 16); }
__device__ __forceinline__ unsigned short f2b(float f) {   // RNE fp32->bf16
    unsigned u = __float_as_uint(f);
    return (unsigned short)((u + 0x7fff + ((u >> 16) & 1)) >> 16);
}

// ---------- prep: weight split+transpose to bf16 hi/lo planes [N][K] + edge scalars + embed
// blocks: [0,144) Wh, [144,336) W1, [336,528) W2, 528 edge scalars, [529,2577) embed h=nf@Wn
__global__ __launch_bounds__(256) void k_prep(
    const float* __restrict__ Wh, const float* __restrict__ W1, const float* __restrict__ W2,
    const float* __restrict__ We_in, const float* __restrict__ We,
    const float* __restrict__ nf, const float* __restrict__ Wn,
    unsigned short* __restrict__ WhH, unsigned short* __restrict__ WhL,
    unsigned short* __restrict__ W1H, unsigned short* __restrict__ W1L,
    unsigned short* __restrict__ W2H, unsigned short* __restrict__ W2L,
    float* __restrict__ sbuf, float* __restrict__ h)
{
    int b = blockIdx.x, t = threadIdx.x;
    if (b >= 529) {                       // embed
        int idx = (b - 529) * 256 + t;
        int r = idx >> 7, c = idx & 127;
        h[idx] = nf[2 * r] * Wn[c] + nf[2 * r + 1] * Wn[HID + c];
        return;
    }
    if (b == 528) {                       // edge scalars (rank-1 collapse of e @ We)
        if (t < NL * 2 * NHEAD) {
            int l = t / (2 * NHEAD), j = t % (2 * NHEAD);
            float acc = 0.f;
            for (int c = 0; c < HID; ++c)
                acc += We_in[c] * We[(long)(l * HID + c) * (2 * NHEAD) + j];
            sbuf[t] = acc;
        }
        return;
    }
    const float* S; unsigned short *OH, *OL; int K, N, kt, nt;
    if (b < 144) {
        int l = b / 48, rem = b % 48; kt = rem & 3; nt = rem >> 2; K = 128; N = 384;
        S = Wh + (long)l * 128 * 384; OH = WhH + (long)l * 384 * 128; OL = WhL + (long)l * 384 * 128;
    } else if (b < 336) {
        int b2 = b - 144; int l = b2 / 64, rem = b2 % 64; kt = rem & 3; nt = rem >> 2; K = 128; N = 512;
        S = W1 + (long)l * 128 * 512; OH = W1H + (long)l * 512 * 128; OL = W1L + (long)l * 512 * 128;
    } else {
        int b2 = b - 336; int l = b2 / 64, rem = b2 % 64; kt = rem & 15; nt = rem >> 4; K = 512; N = 128;
        S = W2 + (long)l * 512 * 128; OH = W2H + (long)l * 128 * 512; OL = W2L + (long)l * 128 * 512;
    }
    __shared__ float sm[32][33];
    int i0 = t >> 5, j = t & 31;
#pragma unroll
    for (int p = 0; p < 4; ++p) {
        int i = i0 + p * 8;
        sm[i][j] = S[(long)(kt * 32 + i) * N + nt * 32 + j];
    }
    __syncthreads();
#pragma unroll
    for (int p = 0; p < 4; ++p) {
        int n = i0 + p * 8;
        float v = sm[j][n];
        unsigned short hh = f2b(v);
        long o = (long)(nt * 32 + n) * K + kt * 32 + j;
        OH[o] = hh; OL[o] = f2b(v - us2f(hh));
    }
}

// ---------- fused LN + split-bf16 MFMA GEMM, K=128 single-shot, 64x64 tile, 4 waves.
// A = LN(x (+x2)) computed in-register, split hi/lo written straight into LDS A-layout.
// mode 0: Cf = acc     mode 1: relu -> Ch/Cl planes
__global__ __launch_bounds__(256) void k_fgemm(
    const float* __restrict__ x, const float* __restrict__ x2,
    const float* __restrict__ g, const float* __restrict__ b,
    const unsigned short* __restrict__ WH, const unsigned short* __restrict__ WL,
    float* __restrict__ Cf, unsigned short* __restrict__ Ch, unsigned short* __restrict__ Cl,
    int Nc, int mode)
{
    __shared__ unsigned short sAh[64 * 136], sAl[64 * 136];   // [m][k] 17.4 KB each
    __shared__ unsigned short sWh[64 * 136], sWl[64 * 136];   // [n][k]
    int t = threadIdx.x;
    int row0 = blockIdx.y * 64, col0 = blockIdx.x * 64;

    // ---- stage W planes (transposed [N][K], coalesced uint4)
#pragma unroll
    for (int p = 0; p < 4; ++p) {
        int rr = (t >> 4) + p * 16, ck = t & 15;
        *(uint4*)&sWh[rr * 136 + ck * 8] = *(const uint4*)&WH[(long)(col0 + rr) * 128 + ck * 8];
        *(uint4*)&sWl[rr * 136 + ck * 8] = *(const uint4*)&WL[(long)(col0 + rr) * 128 + ck * 8];
    }
    // ---- LN of 64 A-rows: 2 passes x 32 rows, 8 threads/row, 16 cols each
#pragma unroll
    for (int pass = 0; pass < 2; ++pass) {
        int row = pass * 32 + (t >> 3);
        int p = t & 7, cb = p * 16;
        float v[16];
        const float* xp = x + (long)(row0 + row) * HID + cb;
#pragma unroll
        for (int j = 0; j < 16; j += 4) *(float4*)&v[j] = *(const float4*)(xp + j);
        if (x2) {
            const float* yp = x2 + (long)(row0 + row) * HID + cb;
#pragma unroll
            for (int j = 0; j < 16; j += 4) {
                float4 r4 = *(const float4*)(yp + j);
                v[j] += r4.x; v[j+1] += r4.y; v[j+2] += r4.z; v[j+3] += r4.w;
            }
        }
        float s = 0.f, s2 = 0.f;
#pragma unroll
        for (int j = 0; j < 16; ++j) { s += v[j]; s2 += v[j] * v[j]; }
        s  += __shfl_xor(s, 1);  s  += __shfl_xor(s, 2);  s  += __shfl_xor(s, 4);
        s2 += __shfl_xor(s2, 1); s2 += __shfl_xor(s2, 2); s2 += __shfl_xor(s2, 4);
        float mu  = s * (1.f / HID);
        float var = s2 * (1.f / HID) - mu * mu;
        float inv = rsqrtf(var + 1e-5f);
        unsigned short hi[16], lo[16];
#pragma unroll
        for (int j = 0; j < 16; ++j) {
            int c = cb + j;
            float o = (v[j] - mu) * inv * g[c] + b[c];
            hi[j] = f2b(o); lo[j] = f2b(o - us2f(hi[j]));
        }
        *(uint4*)&sAh[row * 136 + cb]     = *(uint4*)&hi[0];
        *(uint4*)&sAh[row * 136 + cb + 8] = *(uint4*)&hi[8];
        *(uint4*)&sAl[row * 136 + cb]     = *(uint4*)&lo[0];
        *(uint4*)&sAl[row * 136 + cb + 8] = *(uint4*)&lo[8];
    }
    __syncthreads();

    int w = t >> 6, lane = t & 63;
    int m = lane & 15, quad = lane >> 4;
    f32x4 acc[4];
#pragma unroll
    for (int i = 0; i < 4; ++i) acc[i] = (f32x4){0.f, 0.f, 0.f, 0.f};
#pragma unroll
    for (int c = 0; c < 4; ++c) {
        bf16x8 ah = *(const bf16x8*)&sAh[(w * 16 + m) * 136 + c * 32 + quad * 8];
        bf16x8 al = *(const bf16x8*)&sAl[(w * 16 + m) * 136 + c * 32 + quad * 8];
#pragma unroll
        for (int nt = 0; nt < 4; ++nt) {
            bf16x8 wh = *(const bf16x8*)&sWh[(nt * 16 + m) * 136 + c * 32 + quad * 8];
            bf16x8 wl = *(const bf16x8*)&sWl[(nt * 16 + m) * 136 + c * 32 + quad * 8];
            acc[nt] = __builtin_amdgcn_mfma_f32_16x16x32_bf16(ah, wh, acc[nt], 0, 0, 0);
            acc[nt] = __builtin_amdgcn_mfma_f32_16x16x32_bf16(ah, wl, acc[nt], 0, 0, 0);
            acc[nt] = __builtin_amdgcn_mfma_f32_16x16x32_bf16(al, wh, acc[nt], 0, 0, 0);
        }
    }
#pragma unroll
    for (int nt = 0; nt < 4; ++nt) {
#pragma unroll
        for (int r = 0; r < 4; ++r) {
            int row = row0 + w * 16 + quad * 4 + r;
            int col = col0 + nt * 16 + m;
            float v = acc[nt][r];
            if (mode == 0) {
                Cf[(long)row * Nc + col] = v;
            } else {
                v = fmaxf(v, 0.f);
                unsigned short hh = f2b(v);
                Ch[(long)row * Nc + col] = hh;
                Cl[(long)row * Nc + col] = f2b(v - us2f(hh));
            }
        }
    }
}

// ---------- W2 GEMM + residual (+ fused decode on last layer): 16 rows x 128 cols/block.
__global__ __launch_bounds__(256, 3) void k_w2ln(
    const unsigned short* __restrict__ Ah, const unsigned short* __restrict__ Al,   // [4096][512]
    const unsigned short* __restrict__ WH, const unsigned short* __restrict__ WL,   // [128][512]
    const float* __restrict__ yres, float* __restrict__ hout,
    const float* __restrict__ Wdec, float* __restrict__ out)
{
    __shared__ unsigned short sA[2][16 * 72];
    __shared__ unsigned short sW[2][128 * 72];
    int t = threadIdx.x;
    int row0 = blockIdx.x * 16;
    int w = t >> 6, lane = t & 63;
    int m = lane & 15, quad = lane >> 4;
    f32x4 acc[2];
    acc[0] = (f32x4){0.f,0.f,0.f,0.f}; acc[1] = (f32x4){0.f,0.f,0.f,0.f};

    for (int ks = 0; ks < 512; ks += 64) {
        if (ks) __syncthreads();
        {
            int pl = t >> 7, tt = t & 127;
            int r = tt >> 3, ck = tt & 7;
            const unsigned short* src = pl ? Al : Ah;
            *(uint4*)&sA[pl][r * 72 + ck * 8] = *(const uint4*)&src[(long)(row0 + r) * 512 + ks + ck * 8];
        }
        {
            int r0 = t >> 3, ck = t & 7;
#pragma unroll
            for (int p = 0; p < 4; ++p) {
                int n = r0 + p * 32;
                *(uint4*)&sW[0][n * 72 + ck * 8] = *(const uint4*)&WH[(long)n * 512 + ks + ck * 8];
                *(uint4*)&sW[1][n * 72 + ck * 8] = *(const uint4*)&WL[(long)n * 512 + ks + ck * 8];
            }
        }
        __syncthreads();
#pragma unroll
        for (int c = 0; c < 2; ++c) {
            bf16x8 ah = *(const bf16x8*)&sA[0][m * 72 + c * 32 + quad * 8];
            bf16x8 al = *(const bf16x8*)&sA[1][m * 72 + c * 32 + quad * 8];
#pragma unroll
            for (int nt = 0; nt < 2; ++nt) {
                int n = w * 32 + nt * 16 + m;
                bf16x8 wh = *(const bf16x8*)&sW[0][n * 72 + c * 32 + quad * 8];
                bf16x8 wl = *(const bf16x8*)&sW[1][n * 72 + c * 32 + quad * 8];
                acc[nt] = __builtin_amdgcn_mfma_f32_16x16x32_bf16(ah, wh, acc[nt], 0, 0, 0);
                acc[nt] = __builtin_amdgcn_mfma_f32_16x16x32_bf16(ah, wl, acc[nt], 0, 0, 0);
                acc[nt] = __builtin_amdgcn_mfma_f32_16x16x32_bf16(al, wh, acc[nt], 0, 0, 0);
            }
        }
    }
    __syncthreads();                    // all sW reads done; reuse as fp32 tile
    float* ht = (float*)&sW[0][0];      // [16][132]
#pragma unroll
    for (int nt = 0; nt < 2; ++nt) {
#pragma unroll
        for (int r = 0; r < 4; ++r) {
            int row = quad * 4 + r;
            int col = w * 32 + nt * 16 + m;
            float v = acc[nt][r] + yres[(long)(row0 + row) * HID + col];
            hout[(long)(row0 + row) * HID + col] = v;
            ht[row * 132 + col] = v;
        }
    }
    __syncthreads();
    if (Wdec) {                         // fused decode: out = 10*tanh((h@Wdec)/sqrt(128))
        int row = t >> 4, sub = t & 15;
        float v[8];
        *(float4*)&v[0] = *(const float4*)&ht[row * 132 + sub * 8];
        *(float4*)&v[4] = *(const float4*)&ht[row * 132 + sub * 8 + 4];
        float a = 0.f;
#pragma unroll
        for (int j = 0; j < 8; ++j) a += v[j] * Wdec[sub * 8 + j];
        a += __shfl_xor(a, 1); a += __shfl_xor(a, 2); a += __shfl_xor(a, 4); a += __shfl_xor(a, 8);
        if (sub == 0) out[row0 + row] = 10.f * tanhf(a * 0.08838834764831845f);
    }
}

// ---------- attention: grid 512 = b x head x quarter. Pb per-wave -> no inner barriers.
__global__ __launch_bounds__(256) void k_attn(const float* __restrict__ qkv,
                                              const float* __restrict__ ef,
                                              const float* __restrict__ sbuf,
                                              int layer,
                                              float* __restrict__ y) {
    __shared__ float Ks[NS][20];
    __shared__ float Vt[16][NS + 4];
    __shared__ float Pb[4][4][NS];
    int bid = blockIdx.x;
    int q4 = bid & 3, hh = (bid >> 2) & 7, bb = bid >> 5;
    int t = threadIdx.x;
    {
        const float* kr = qkv + ((long)(bb * NS + t)) * 384 + HID + hh * 16;
        *(float4*)&Ks[t][0]  = *(const float4*)kr;
        *(float4*)&Ks[t][4]  = *(const float4*)(kr + 4);
        *(float4*)&Ks[t][8]  = *(const float4*)(kr + 8);
        *(float4*)&Ks[t][12] = *(const float4*)(kr + 12);
        const float* vr = kr + HID;
        float vv[16];
        *(float4*)&vv[0]  = *(const float4*)vr;
        *(float4*)&vv[4]  = *(const float4*)(vr + 4);
        *(float4*)&vv[8]  = *(const float4*)(vr + 8);
        *(float4*)&vv[12] = *(const float4*)(vr + 12);
#pragma unroll
        for (int d = 0; d < 16; ++d) Vt[d][t] = vv[d];
    }
    __syncthreads();
    int w = t >> 6, lane = t & 63;
    float s1  = sbuf[layer * 16 + hh];
    float s2g = sbuf[layer * 16 + NHEAD + hh];
    int part = lane >> 4, dd = lane & 15;
    for (int it = 0; it < 4; ++it) {
        int r0 = q4 * 64 + w * 16 + it * 4;
        float q[4][16];
#pragma unroll
        for (int rr = 0; rr < 4; ++rr) {
            const float* qr = qkv + ((long)(bb * NS + r0 + rr)) * 384 + hh * 16;
            *(float4*)&q[rr][0]  = *(const float4*)qr;
            *(float4*)&q[rr][4]  = *(const float4*)(qr + 4);
            *(float4*)&q[rr][8]  = *(const float4*)(qr + 8);
            *(float4*)&q[rr][12] = *(const float4*)(qr + 12);
        }
        float sc[4][4];
#pragma unroll
        for (int i = 0; i < 4; ++i) {
            int c = i * 64 + lane;
            float kk[16];
            *(float4*)&kk[0]  = *(const float4*)&Ks[c][0];
            *(float4*)&kk[4]  = *(const float4*)&Ks[c][4];
            *(float4*)&kk[8]  = *(const float4*)&Ks[c][8];
            *(float4*)&kk[12] = *(const float4*)&Ks[c][12];
#pragma unroll
            for (int rr = 0; rr < 4; ++rr) {
                float d0 = 0.f;
#pragma unroll
                for (int d = 0; d < 16; ++d) d0 += q[rr][d] * kk[d];
                sc[rr][i] = d0;
            }
        }
#pragma unroll
        for (int rr = 0; rr < 4; ++rr) {
            long eb = ((long)(bb * NS + r0 + rr)) * NS;
            float e0 = ef[eb + lane],       e1 = ef[eb + 64 + lane];
            float e2 = ef[eb + 128 + lane], e3 = ef[eb + 192 + lane];
            float x0 = sc[rr][0] * 0.25f + e0 * s1;
            float x1 = sc[rr][1] * 0.25f + e1 * s1;
            float x2 = sc[rr][2] * 0.25f + e2 * s1;
            float x3 = sc[rr][3] * 0.25f + e3 * s1;
            float m = fmaxf(fmaxf(x0, x1), fmaxf(x2, x3));
#pragma unroll
            for (int o = 32; o; o >>= 1) m = fmaxf(m, __shfl_xor(m, o));
            float p0 = __expf(x0 - m), p1 = __expf(x1 - m);
            float p2 = __expf(x2 - m), p3 = __expf(x3 - m);
            float sum = p0 + p1 + p2 + p3;
#pragma unroll
            for (int o = 32; o; o >>= 1) sum += __shfl_xor(sum, o);
            float inv = s2g / sum;
            Pb[w][rr][lane]       = p0 * inv * e0;
            Pb[w][rr][64 + lane]  = p1 * inv * e1;
            Pb[w][rr][128 + lane] = p2 * inv * e2;
            Pb[w][rr][192 + lane] = p3 * inv * e3;
        }
        float a0 = 0.f, a1 = 0.f, a2 = 0.f, a3 = 0.f;
#pragma unroll
        for (int ii = 0; ii < 16; ++ii) {
            int c = part * 64 + ((ii + part * 4) & 15) * 4;
            float4 vv = *(const float4*)&Vt[dd][c];
            float4 p;
            p = *(const float4*)&Pb[w][0][c]; a0 += vv.x*p.x + vv.y*p.y + vv.z*p.z + vv.w*p.w;
            p = *(const float4*)&Pb[w][1][c]; a1 += vv.x*p.x + vv.y*p.y + vv.z*p.z + vv.w*p.w;
            p = *(const float4*)&Pb[w][2][c]; a2 += vv.x*p.x + vv.y*p.y + vv.z*p.z + vv.w*p.w;
            p = *(const float4*)&Pb[w][3][c]; a3 += vv.x*p.x + vv.y*p.y + vv.z*p.z + vv.w*p.w;
        }
        a0 += __shfl_xor(a0, 16); a0 += __shfl_xor(a0, 32);
        a1 += __shfl_xor(a1, 16); a1 += __shfl_xor(a1, 32);
        a2 += __shfl_xor(a2, 16); a2 += __shfl_xor(a2, 32);
        a3 += __shfl_xor(a3, 16); a3 += __shfl_xor(a3, 32);
        if (lane < 16) {
            y[((long)(bb * NS + r0 + 0)) * HID + hh * 16 + dd] = a0;
            y[((long)(bb * NS + r0 + 1)) * HID + hh * 16 + dd] = a1;
            y[((long)(bb * NS + r0 + 2)) * HID + hh * 16 + dd] = a2;
            y[((long)(bb * NS + r0 + 3)) * HID + hh * 16 + dd] = a3;
        }
    }
}

extern "C" void kernel_launch(void* const* d_in, const int* in_sizes, int n_in,
                              void* d_out, int out_size, void* d_ws, size_t ws_size,
                              hipStream_t stream) {
    const float* nf    = (const float*)d_in[0];
    const float* ef    = (const float*)d_in[1];
    const float* Wn    = (const float*)d_in[2];
    const float* We_in = (const float*)d_in[3];
    const float* ln1g  = (const float*)d_in[4];
    const float* ln1b  = (const float*)d_in[5];
    const float* Wh    = (const float*)d_in[6];
    const float* We    = (const float*)d_in[7];
    const float* ln2g  = (const float*)d_in[8];
    const float* ln2b  = (const float*)d_in[9];
    const float* W1    = (const float*)d_in[10];
    const float* W2    = (const float*)d_in[11];
    const float* Wdec  = (const float*)d_in[12];

    float* ws   = (float*)d_ws;
    float* sbuf = ws;                            // 64 slots
    float* h    = ws + 64;                       // 4096*128
    float* y    = h + ROWS * HID;                // 4096*128
    float* qkv  = y + ROWS * HID;                // 4096*384
    unsigned short* hidH = (unsigned short*)(qkv + (long)ROWS * 384);   // 4096*512
    unsigned short* hidL = hidH + (long)ROWS * 512;
    unsigned short* WhH  = hidL + (long)ROWS * 512;          // 3*384*128
    unsigned short* WhL  = WhH + (long)NL * 384 * 128;
    unsigned short* W1H  = WhL + (long)NL * 384 * 128;       // 3*512*128
    unsigned short* W1L  = W1H + (long)NL * 512 * 128;
    unsigned short* W2H  = W1L + (long)NL * 512 * 128;       // 3*128*512
    unsigned short* W2L  = W2H + (long)NL * 128 * 512;

    k_prep<<<529 + ROWS * HID / 256, 256, 0, stream>>>(Wh, W1, W2, We_in, We, nf, Wn,
                                    WhH, WhL, W1H, W1L, W2H, W2L, sbuf, h);
    for (int l = 0; l < NL; ++l) {
        // LN1 + QKV GEMM
        k_fgemm<<<dim3(6, 64), 256, 0, stream>>>(h, nullptr,
            ln1g + l * HID, ln1b + l * HID,
            WhH + (long)l * 384 * 128, WhL + (long)l * 384 * 128,
            qkv, nullptr, nullptr, 384, 0);
        k_attn<<<512, 256, 0, stream>>>(qkv, ef, sbuf, l, y);
        // LN2(y+h) + W1 GEMM + relu -> planes
        k_fgemm<<<dim3(8, 64), 256, 0, stream>>>(y, h,
            ln2g + l * HID, ln2b + l * HID,
            W1H + (long)l * 512 * 128, W1L + (long)l * 512 * 128,
            nullptr, hidH, hidL, 512, 1);
        // W2 GEMM + residual -> h (+ decode on last layer)
        int last = (l == NL - 1);
        k_w2ln<<<ROWS / 16, 256, 0, stream>>>(hidH, hidL,
            W2H + (long)l * 128 * 512, W2L + (long)l * 128 * 512,
            y, h, last ? Wdec : nullptr, (float*)d_out);
    }
}

// Round 9
// 231.559 us; speedup vs baseline: 1.0662x; 1.0662x over previous
//
#include <hip/hip_runtime.h>
#include <math.h>

#define HID 128
#define NHEAD 8
#define NL 3
#define NS 256
#define ROWS 4096

typedef __attribute__((ext_vector_type(8))) short bf16x8;
typedef __attribute__((ext_vector_type(4))) float f32x4;

__device__ __forceinline__ float us2f(unsigned short s) { return __uint_as_float(((unsigned)s) << 16); }
__device__ __forceinline__ unsigned short f2b(float f) {   // RNE fp32->bf16
    unsigned u = __float_as_uint(f);
    return (unsigned short)((u + 0x7fff + ((u >> 16) & 1)) >> 16);
}

// ---------- prep: weight split+transpose to bf16 hi/lo planes [N][K] + edge scalars + embed
// blocks: [0,144) Wh, [144,336) W1, [336,528) W2, 528 edge scalars, [529,2577) embed h=nf@Wn
__global__ __launch_bounds__(256) void k_prep(
    const float* __restrict__ Wh, const float* __restrict__ W1, const float* __restrict__ W2,
    const float* __restrict__ We_in, const float* __restrict__ We,
    const float* __restrict__ nf, const float* __restrict__ Wn,
    unsigned short* __restrict__ WhH, unsigned short* __restrict__ WhL,
    unsigned short* __restrict__ W1H, unsigned short* __restrict__ W1L,
    unsigned short* __restrict__ W2H, unsigned short* __restrict__ W2L,
    float* __restrict__ sbuf, float* __restrict__ h)
{
    int b = blockIdx.x, t = threadIdx.x;
    if (b >= 529) {                       // embed
        int idx = (b - 529) * 256 + t;
        int r = idx >> 7, c = idx & 127;
        h[idx] = nf[2 * r] * Wn[c] + nf[2 * r + 1] * Wn[HID + c];
        return;
    }
    if (b == 528) {                       // edge scalars (rank-1 collapse of e @ We)
        if (t < NL * 2 * NHEAD) {
            int l = t / (2 * NHEAD), j = t % (2 * NHEAD);
            float acc = 0.f;
            for (int c = 0; c < HID; ++c)
                acc += We_in[c] * We[(long)(l * HID + c) * (2 * NHEAD) + j];
            sbuf[t] = acc;
        }
        return;
    }
    const float* S; unsigned short *OH, *OL; int K, N, kt, nt;
    if (b < 144) {
        int l = b / 48, rem = b % 48; kt = rem & 3; nt = rem >> 2; K = 128; N = 384;
        S = Wh + (long)l * 128 * 384; OH = WhH + (long)l * 384 * 128; OL = WhL + (long)l * 384 * 128;
    } else if (b < 336) {
        int b2 = b - 144; int l = b2 / 64, rem = b2 % 64; kt = rem & 3; nt = rem >> 2; K = 128; N = 512;
        S = W1 + (long)l * 128 * 512; OH = W1H + (long)l * 512 * 128; OL = W1L + (long)l * 512 * 128;
    } else {
        int b2 = b - 336; int l = b2 / 64, rem = b2 % 64; kt = rem & 15; nt = rem >> 4; K = 512; N = 128;
        S = W2 + (long)l * 512 * 128; OH = W2H + (long)l * 128 * 512; OL = W2L + (long)l * 128 * 512;
    }
    __shared__ float sm[32][33];
    int i0 = t >> 5, j = t & 31;
#pragma unroll
    for (int p = 0; p < 4; ++p) {
        int i = i0 + p * 8;
        sm[i][j] = S[(long)(kt * 32 + i) * N + nt * 32 + j];
    }
    __syncthreads();
#pragma unroll
    for (int p = 0; p < 4; ++p) {
        int n = i0 + p * 8;
        float v = sm[j][n];
        unsigned short hh = f2b(v);
        long o = (long)(nt * 32 + n) * K + kt * 32 + j;
        OH[o] = hh; OL[o] = f2b(v - us2f(hh));
    }
}

// ---------- fused LN + split-bf16 MFMA GEMM, K=128 single-shot, 64x64 tile, 4 waves.
// mode 0: Cf = acc     mode 1: relu -> Ch/Cl planes
__global__ __launch_bounds__(256) void k_fgemm(
    const float* __restrict__ x, const float* __restrict__ x2,
    const float* __restrict__ g, const float* __restrict__ b,
    const unsigned short* __restrict__ WH, const unsigned short* __restrict__ WL,
    float* __restrict__ Cf, unsigned short* __restrict__ Ch, unsigned short* __restrict__ Cl,
    int Nc, int mode)
{
    __shared__ unsigned short sAh[64 * 136], sAl[64 * 136];   // [m][k]
    __shared__ unsigned short sWh[64 * 136], sWl[64 * 136];   // [n][k]
    int t = threadIdx.x;
    int row0 = blockIdx.y * 64, col0 = blockIdx.x * 64;

#pragma unroll
    for (int p = 0; p < 4; ++p) {
        int rr = (t >> 4) + p * 16, ck = t & 15;
        *(uint4*)&sWh[rr * 136 + ck * 8] = *(const uint4*)&WH[(long)(col0 + rr) * 128 + ck * 8];
        *(uint4*)&sWl[rr * 136 + ck * 8] = *(const uint4*)&WL[(long)(col0 + rr) * 128 + ck * 8];
    }
#pragma unroll
    for (int pass = 0; pass < 2; ++pass) {
        int row = pass * 32 + (t >> 3);
        int p = t & 7, cb = p * 16;
        float v[16];
        const float* xp = x + (long)(row0 + row) * HID + cb;
#pragma unroll
        for (int j = 0; j < 16; j += 4) *(float4*)&v[j] = *(const float4*)(xp + j);
        if (x2) {
            const float* yp = x2 + (long)(row0 + row) * HID + cb;
#pragma unroll
            for (int j = 0; j < 16; j += 4) {
                float4 r4 = *(const float4*)(yp + j);
                v[j] += r4.x; v[j+1] += r4.y; v[j+2] += r4.z; v[j+3] += r4.w;
            }
        }
        float s = 0.f, s2 = 0.f;
#pragma unroll
        for (int j = 0; j < 16; ++j) { s += v[j]; s2 += v[j] * v[j]; }
        s  += __shfl_xor(s, 1);  s  += __shfl_xor(s, 2);  s  += __shfl_xor(s, 4);
        s2 += __shfl_xor(s2, 1); s2 += __shfl_xor(s2, 2); s2 += __shfl_xor(s2, 4);
        float mu  = s * (1.f / HID);
        float var = s2 * (1.f / HID) - mu * mu;
        float inv = rsqrtf(var + 1e-5f);
        unsigned short hi[16], lo[16];
#pragma unroll
        for (int j = 0; j < 16; ++j) {
            int c = cb + j;
            float o = (v[j] - mu) * inv * g[c] + b[c];
            hi[j] = f2b(o); lo[j] = f2b(o - us2f(hi[j]));
        }
        *(uint4*)&sAh[row * 136 + cb]     = *(uint4*)&hi[0];
        *(uint4*)&sAh[row * 136 + cb + 8] = *(uint4*)&hi[8];
        *(uint4*)&sAl[row * 136 + cb]     = *(uint4*)&lo[0];
        *(uint4*)&sAl[row * 136 + cb + 8] = *(uint4*)&lo[8];
    }
    __syncthreads();

    int w = t >> 6, lane = t & 63;
    int m = lane & 15, quad = lane >> 4;
    f32x4 acc[4];
#pragma unroll
    for (int i = 0; i < 4; ++i) acc[i] = (f32x4){0.f, 0.f, 0.f, 0.f};
#pragma unroll
    for (int c = 0; c < 4; ++c) {
        bf16x8 ah = *(const bf16x8*)&sAh[(w * 16 + m) * 136 + c * 32 + quad * 8];
        bf16x8 al = *(const bf16x8*)&sAl[(w * 16 + m) * 136 + c * 32 + quad * 8];
#pragma unroll
        for (int nt = 0; nt < 4; ++nt) {
            bf16x8 wh = *(const bf16x8*)&sWh[(nt * 16 + m) * 136 + c * 32 + quad * 8];
            bf16x8 wl = *(const bf16x8*)&sWl[(nt * 16 + m) * 136 + c * 32 + quad * 8];
            acc[nt] = __builtin_amdgcn_mfma_f32_16x16x32_bf16(ah, wh, acc[nt], 0, 0, 0);
            acc[nt] = __builtin_amdgcn_mfma_f32_16x16x32_bf16(ah, wl, acc[nt], 0, 0, 0);
            acc[nt] = __builtin_amdgcn_mfma_f32_16x16x32_bf16(al, wh, acc[nt], 0, 0, 0);
        }
    }
#pragma unroll
    for (int nt = 0; nt < 4; ++nt) {
#pragma unroll
        for (int r = 0; r < 4; ++r) {
            int row = row0 + w * 16 + quad * 4 + r;
            int col = col0 + nt * 16 + m;
            float v = acc[nt][r];
            if (mode == 0) {
                Cf[(long)row * Nc + col] = v;
            } else {
                v = fmaxf(v, 0.f);
                unsigned short hh = f2b(v);
                Ch[(long)row * Nc + col] = hh;
                Cl[(long)row * Nc + col] = f2b(v - us2f(hh));
            }
        }
    }
}

// ---------- W2 GEMM + residual (+ fused decode on last layer): 16 rows x 128 cols/block.
__global__ __launch_bounds__(256, 3) void k_w2ln(
    const unsigned short* __restrict__ Ah, const unsigned short* __restrict__ Al,   // [4096][512]
    const unsigned short* __restrict__ WH, const unsigned short* __restrict__ WL,   // [128][512]
    const float* __restrict__ yres, float* __restrict__ hout,
    const float* __restrict__ Wdec, float* __restrict__ out)
{
    __shared__ unsigned short sA[2][16 * 72];
    __shared__ unsigned short sW[2][128 * 72];
    int t = threadIdx.x;
    int row0 = blockIdx.x * 16;
    int w = t >> 6, lane = t & 63;
    int m = lane & 15, quad = lane >> 4;
    f32x4 acc[2];
    acc[0] = (f32x4){0.f,0.f,0.f,0.f}; acc[1] = (f32x4){0.f,0.f,0.f,0.f};

    for (int ks = 0; ks < 512; ks += 64) {
        if (ks) __syncthreads();
        {
            int pl = t >> 7, tt = t & 127;
            int r = tt >> 3, ck = tt & 7;
            const unsigned short* src = pl ? Al : Ah;
            *(uint4*)&sA[pl][r * 72 + ck * 8] = *(const uint4*)&src[(long)(row0 + r) * 512 + ks + ck * 8];
        }
        {
            int r0 = t >> 3, ck = t & 7;
#pragma unroll
            for (int p = 0; p < 4; ++p) {
                int n = r0 + p * 32;
                *(uint4*)&sW[0][n * 72 + ck * 8] = *(const uint4*)&WH[(long)n * 512 + ks + ck * 8];
                *(uint4*)&sW[1][n * 72 + ck * 8] = *(const uint4*)&WL[(long)n * 512 + ks + ck * 8];
            }
        }
        __syncthreads();
#pragma unroll
        for (int c = 0; c < 2; ++c) {
            bf16x8 ah = *(const bf16x8*)&sA[0][m * 72 + c * 32 + quad * 8];
            bf16x8 al = *(const bf16x8*)&sA[1][m * 72 + c * 32 + quad * 8];
#pragma unroll
            for (int nt = 0; nt < 2; ++nt) {
                int n = w * 32 + nt * 16 + m;
                bf16x8 wh = *(const bf16x8*)&sW[0][n * 72 + c * 32 + quad * 8];
                bf16x8 wl = *(const bf16x8*)&sW[1][n * 72 + c * 32 + quad * 8];
                acc[nt] = __builtin_amdgcn_mfma_f32_16x16x32_bf16(ah, wh, acc[nt], 0, 0, 0);
                acc[nt] = __builtin_amdgcn_mfma_f32_16x16x32_bf16(ah, wl, acc[nt], 0, 0, 0);
                acc[nt] = __builtin_amdgcn_mfma_f32_16x16x32_bf16(al, wh, acc[nt], 0, 0, 0);
            }
        }
    }
    __syncthreads();                    // all sW reads done; reuse as fp32 tile
    float* ht = (float*)&sW[0][0];      // [16][132]
#pragma unroll
    for (int nt = 0; nt < 2; ++nt) {
#pragma unroll
        for (int r = 0; r < 4; ++r) {
            int row = quad * 4 + r;
            int col = w * 32 + nt * 16 + m;
            float v = acc[nt][r] + yres[(long)(row0 + row) * HID + col];
            hout[(long)(row0 + row) * HID + col] = v;
            ht[row * 132 + col] = v;
        }
    }
    __syncthreads();
    if (Wdec) {                         // fused decode: out = 10*tanh((h@Wdec)/sqrt(128))
        int row = t >> 4, sub = t & 15;
        float v[8];
        *(float4*)&v[0] = *(const float4*)&ht[row * 132 + sub * 8];
        *(float4*)&v[4] = *(const float4*)&ht[row * 132 + sub * 8 + 4];
        float a = 0.f;
#pragma unroll
        for (int j = 0; j < 8; ++j) a += v[j] * Wdec[sub * 8 + j];
        a += __shfl_xor(a, 1); a += __shfl_xor(a, 2); a += __shfl_xor(a, 4); a += __shfl_xor(a, 8);
        if (sub == 0) out[row0 + row] = 10.f * tanhf(a * 0.08838834764831845f);
    }
}

// ---------- attention: grid 512 = b x head x quarter; 4 waves x 16 q-rows.
// QK^T + softmax in fp32 VALU (Ks in LDS); PV via MFMA: P -> per-wave bf16 A-plane,
// V -> transposed bf16 hi/lo B-planes. DS traffic ~4x lower than Pb-roundtrip version.
#define PAS (NS + 8)
__global__ __launch_bounds__(256) void k_attn(const float* __restrict__ qkv,
                                              const float* __restrict__ ef,
                                              const float* __restrict__ sbuf,
                                              int layer,
                                              float* __restrict__ y) {
    __shared__ float Ks[NS][20];                     // 20.5 KB
    __shared__ unsigned short Vh[16][PAS];           // [d][key] 8.4 KB
    __shared__ unsigned short Vl[16][PAS];
    __shared__ unsigned short Pa[4][16][PAS];        // per-wave [qrow][key] 33.8 KB
    int bid = blockIdx.x;
    int q4 = bid & 3, hh = (bid >> 2) & 7, bb = bid >> 5;
    int t = threadIdx.x;
    {   // stage K fp32 + V bf16 hi/lo transposed
        const float* kr = qkv + ((long)(bb * NS + t)) * 384 + HID + hh * 16;
        *(float4*)&Ks[t][0]  = *(const float4*)kr;
        *(float4*)&Ks[t][4]  = *(const float4*)(kr + 4);
        *(float4*)&Ks[t][8]  = *(const float4*)(kr + 8);
        *(float4*)&Ks[t][12] = *(const float4*)(kr + 12);
        const float* vr = kr + HID;
        float vv[16];
        *(float4*)&vv[0]  = *(const float4*)vr;
        *(float4*)&vv[4]  = *(const float4*)(vr + 4);
        *(float4*)&vv[8]  = *(const float4*)(vr + 8);
        *(float4*)&vv[12] = *(const float4*)(vr + 12);
#pragma unroll
        for (int d = 0; d < 16; ++d) {
            unsigned short hi = f2b(vv[d]);
            Vh[d][t] = hi;
            Vl[d][t] = f2b(vv[d] - us2f(hi));
        }
    }
    __syncthreads();
    int w = t >> 6, lane = t & 63;
    float s1  = sbuf[layer * 16 + hh];
    float s2g = sbuf[layer * 16 + NHEAD + hh];
    int m = lane & 15, quad = lane >> 4;
    unsigned short* Paw = &Pa[w][0][0];
    for (int it = 0; it < 4; ++it) {
        int r0 = q4 * 64 + w * 16 + it * 4;
        float q[4][16];
#pragma unroll
        for (int rr = 0; rr < 4; ++rr) {
            const float* qr = qkv + ((long)(bb * NS + r0 + rr)) * 384 + hh * 16;
            *(float4*)&q[rr][0]  = *(const float4*)qr;
            *(float4*)&q[rr][4]  = *(const float4*)(qr + 4);
            *(float4*)&q[rr][8]  = *(const float4*)(qr + 8);
            *(float4*)&q[rr][12] = *(const float4*)(qr + 12);
        }
        float sc[4][4];
#pragma unroll
        for (int i = 0; i < 4; ++i) {
            int c = i * 64 + lane;
            float kk[16];
            *(float4*)&kk[0]  = *(const float4*)&Ks[c][0];
            *(float4*)&kk[4]  = *(const float4*)&Ks[c][4];
            *(float4*)&kk[8]  = *(const float4*)&Ks[c][8];
            *(float4*)&kk[12] = *(const float4*)&Ks[c][12];
#pragma unroll
            for (int rr = 0; rr < 4; ++rr) {
                float d0 = 0.f;
#pragma unroll
                for (int d = 0; d < 16; ++d) d0 += q[rr][d] * kk[d];
                sc[rr][i] = d0;
            }
        }
#pragma unroll
        for (int rr = 0; rr < 4; ++rr) {
            long eb = ((long)(bb * NS + r0 + rr)) * NS;
            float e0 = ef[eb + lane],       e1 = ef[eb + 64 + lane];
            float e2 = ef[eb + 128 + lane], e3 = ef[eb + 192 + lane];
            float x0 = sc[rr][0] * 0.25f + e0 * s1;
            float x1 = sc[rr][1] * 0.25f + e1 * s1;
            float x2 = sc[rr][2] * 0.25f + e2 * s1;
            float x3 = sc[rr][3] * 0.25f + e3 * s1;
            float mm = fmaxf(fmaxf(x0, x1), fmaxf(x2, x3));
#pragma unroll
            for (int o = 32; o; o >>= 1) mm = fmaxf(mm, __shfl_xor(mm, o));
            float p0 = __expf(x0 - mm), p1 = __expf(x1 - mm);
            float p2 = __expf(x2 - mm), p3 = __expf(x3 - mm);
            float sum = p0 + p1 + p2 + p3;
#pragma unroll
            for (int o = 32; o; o >>= 1) sum += __shfl_xor(sum, o);
            float inv = s2g / sum;
            int prow = it * 4 + rr;     // q-row within this wave's 16-row strip
            Paw[prow * PAS + lane]       = f2b(p0 * inv * e0);
            Paw[prow * PAS + 64 + lane]  = f2b(p1 * inv * e1);
            Paw[prow * PAS + 128 + lane] = f2b(p2 * inv * e2);
            Paw[prow * PAS + 192 + lane] = f2b(p3 * inv * e3);
        }
    }
    // PV via MFMA (per-wave Pa: no barrier; lgkmcnt covers RAW)
    f32x4 acc = (f32x4){0.f, 0.f, 0.f, 0.f};
#pragma unroll
    for (int s = 0; s < 8; ++s) {
        bf16x8 pf = *(const bf16x8*)&Paw[m * PAS + s * 32 + quad * 8];
        bf16x8 vh = *(const bf16x8*)&Vh[m][s * 32 + quad * 8];
        bf16x8 vl = *(const bf16x8*)&Vl[m][s * 32 + quad * 8];
        acc = __builtin_amdgcn_mfma_f32_16x16x32_bf16(pf, vh, acc, 0, 0, 0);
        acc = __builtin_amdgcn_mfma_f32_16x16x32_bf16(pf, vl, acc, 0, 0, 0);
    }
#pragma unroll
    for (int r = 0; r < 4; ++r) {
        int row = q4 * 64 + w * 16 + quad * 4 + r;
        y[((long)(bb * NS + row)) * HID + hh * 16 + m] = acc[r];
    }
}

extern "C" void kernel_launch(void* const* d_in, const int* in_sizes, int n_in,
                              void* d_out, int out_size, void* d_ws, size_t ws_size,
                              hipStream_t stream) {
    const float* nf    = (const float*)d_in[0];
    const float* ef    = (const float*)d_in[1];
    const float* Wn    = (const float*)d_in[2];
    const float* We_in = (const float*)d_in[3];
    const float* ln1g  = (const float*)d_in[4];
    const float* ln1b  = (const float*)d_in[5];
    const float* Wh    = (const float*)d_in[6];
    const float* We    = (const float*)d_in[7];
    const float* ln2g  = (const float*)d_in[8];
    const float* ln2b  = (const float*)d_in[9];
    const float* W1    = (const float*)d_in[10];
    const float* W2    = (const float*)d_in[11];
    const float* Wdec  = (const float*)d_in[12];

    float* ws   = (float*)d_ws;
    float* sbuf = ws;                            // 64 slots
    float* h    = ws + 64;                       // 4096*128
    float* y    = h + ROWS * HID;                // 4096*128
    float* qkv  = y + ROWS * HID;                // 4096*384
    unsigned short* hidH = (unsigned short*)(qkv + (long)ROWS * 384);   // 4096*512
    unsigned short* hidL = hidH + (long)ROWS * 512;
    unsigned short* WhH  = hidL + (long)ROWS * 512;          // 3*384*128
    unsigned short* WhL  = WhH + (long)NL * 384 * 128;
    unsigned short* W1H  = WhL + (long)NL * 384 * 128;       // 3*512*128
    unsigned short* W1L  = W1H + (long)NL * 512 * 128;
    unsigned short* W2H  = W1L + (long)NL * 512 * 128;       // 3*128*512
    unsigned short* W2L  = W2H + (long)NL * 128 * 512;

    k_prep<<<529 + ROWS * HID / 256, 256, 0, stream>>>(Wh, W1, W2, We_in, We, nf, Wn,
                                    WhH, WhL, W1H, W1L, W2H, W2L, sbuf, h);
    for (int l = 0; l < NL; ++l) {
        // LN1 + QKV GEMM
        k_fgemm<<<dim3(6, 64), 256, 0, stream>>>(h, nullptr,
            ln1g + l * HID, ln1b + l * HID,
            WhH + (long)l * 384 * 128, WhL + (long)l * 384 * 128,
            qkv, nullptr, nullptr, 384, 0);
        k_attn<<<512, 256, 0, stream>>>(qkv, ef, sbuf, l, y);
        // LN2(y+h) + W1 GEMM + relu -> planes
        k_fgemm<<<dim3(8, 64), 256, 0, stream>>>(y, h,
            ln2g + l * HID, ln2b + l * HID,
            W1H + (long)l * 512 * 128, W1L + (long)l * 512 * 128,
            nullptr, hidH, hidL, 512, 1);
        // W2 GEMM + residual -> h (+ decode on last layer)
        int last = (l == NL - 1);
        k_w2ln<<<ROWS / 16, 256, 0, stream>>>(hidH, hidL,
            W2H + (long)l * 128 * 512, W2L + (long)l * 128 * 512,
            y, h, last ? Wdec : nullptr, (float*)d_out);
    }
}

// Round 11
// 231.058 us; speedup vs baseline: 1.0685x; 1.0022x over previous
//
#include <hip/hip_runtime.h>
#include <math.h>

#define HID 128
#define NHEAD 8
#define NL 3
#define NS 256
#define ROWS 4096

typedef __attribute__((ext_vector_type(8))) short bf16x8;
typedef __attribute__((ext_vector_type(4))) float f32x4;

__device__ __forceinline__ float us2f(unsigned short s) { return __uint_as_float(((unsigned)s) << 16); }
__device__ __forceinline__ unsigned short f2b(float f) {   // RNE fp32->bf16
    unsigned u = __float_as_uint(f);
    return (unsigned short)((u + 0x7fff + ((u >> 16) & 1)) >> 16);
}

// ---------- prep: weight split+transpose to bf16 hi/lo planes [N][K] + edge scalars + embed
// blocks: [0,144) Wh, [144,336) W1, [336,528) W2, 528 edge scalars, [529,2577) embed h=nf@Wn
__global__ __launch_bounds__(256) void k_prep(
    const float* __restrict__ Wh, const float* __restrict__ W1, const float* __restrict__ W2,
    const float* __restrict__ We_in, const float* __restrict__ We,
    const float* __restrict__ nf, const float* __restrict__ Wn,
    unsigned short* __restrict__ WhH, unsigned short* __restrict__ WhL,
    unsigned short* __restrict__ W1H, unsigned short* __restrict__ W1L,
    unsigned short* __restrict__ W2H, unsigned short* __restrict__ W2L,
    float* __restrict__ sbuf, float* __restrict__ h)
{
    int b = blockIdx.x, t = threadIdx.x;
    if (b >= 529) {                       // embed
        int idx = (b - 529) * 256 + t;
        int r = idx >> 7, c = idx & 127;
        h[idx] = nf[2 * r] * Wn[c] + nf[2 * r + 1] * Wn[HID + c];
        return;
    }
    if (b == 528) {                       // edge scalars (rank-1 collapse of e @ We)
        if (t < NL * 2 * NHEAD) {
            int l = t / (2 * NHEAD), j = t % (2 * NHEAD);
            float acc = 0.f;
            for (int c = 0; c < HID; ++c)
                acc += We_in[c] * We[(long)(l * HID + c) * (2 * NHEAD) + j];
            sbuf[t] = acc;
        }
        return;
    }
    const float* S; unsigned short *OH, *OL; int K, N, kt, nt;
    if (b < 144) {
        int l = b / 48, rem = b % 48; kt = rem & 3; nt = rem >> 2; K = 128; N = 384;
        S = Wh + (long)l * 128 * 384; OH = WhH + (long)l * 384 * 128; OL = WhL + (long)l * 384 * 128;
    } else if (b < 336) {
        int b2 = b - 144; int l = b2 / 64, rem = b2 % 64; kt = rem & 3; nt = rem >> 2; K = 128; N = 512;
        S = W1 + (long)l * 128 * 512; OH = W1H + (long)l * 512 * 128; OL = W1L + (long)l * 512 * 128;
    } else {
        int b2 = b - 336; int l = b2 / 64, rem = b2 % 64; kt = rem & 15; nt = rem >> 4; K = 512; N = 128;
        S = W2 + (long)l * 512 * 128; OH = W2H + (long)l * 128 * 512; OL = W2L + (long)l * 128 * 512;
    }
    __shared__ float sm[32][33];
    int i0 = t >> 5, j = t & 31;
#pragma unroll
    for (int p = 0; p < 4; ++p) {
        int i = i0 + p * 8;
        sm[i][j] = S[(long)(kt * 32 + i) * N + nt * 32 + j];
    }
    __syncthreads();
#pragma unroll
    for (int p = 0; p < 4; ++p) {
        int n = i0 + p * 8;
        float v = sm[j][n];
        unsigned short hh = f2b(v);
        long o = (long)(nt * 32 + n) * K + kt * 32 + j;
        OH[o] = hh; OL[o] = f2b(v - us2f(hh));
    }
}

// ---------- fused LN + split-bf16 MFMA GEMM, K=128 single-shot, 64x64 tile, 4 waves.
// mode 0: Cf = acc     mode 1: relu -> Ch/Cl planes
__global__ __launch_bounds__(256) void k_fgemm(
    const float* __restrict__ x, const float* __restrict__ x2,
    const float* __restrict__ g, const float* __restrict__ b,
    const unsigned short* __restrict__ WH, const unsigned short* __restrict__ WL,
    float* __restrict__ Cf, unsigned short* __restrict__ Ch, unsigned short* __restrict__ Cl,
    int Nc, int mode)
{
    __shared__ unsigned short sAh[64 * 136], sAl[64 * 136];   // [m][k]
    __shared__ unsigned short sWh[64 * 136], sWl[64 * 136];   // [n][k]
    int t = threadIdx.x;
    int row0 = blockIdx.y * 64, col0 = blockIdx.x * 64;

#pragma unroll
    for (int p = 0; p < 4; ++p) {
        int rr = (t >> 4) + p * 16, ck = t & 15;
        *(uint4*)&sWh[rr * 136 + ck * 8] = *(const uint4*)&WH[(long)(col0 + rr) * 128 + ck * 8];
        *(uint4*)&sWl[rr * 136 + ck * 8] = *(const uint4*)&WL[(long)(col0 + rr) * 128 + ck * 8];
    }
#pragma unroll
    for (int pass = 0; pass < 2; ++pass) {
        int row = pass * 32 + (t >> 3);
        int p = t & 7, cb = p * 16;
        float v[16];
        const float* xp = x + (long)(row0 + row) * HID + cb;
#pragma unroll
        for (int j = 0; j < 16; j += 4) *(float4*)&v[j] = *(const float4*)(xp + j);
        if (x2) {
            const float* yp = x2 + (long)(row0 + row) * HID + cb;
#pragma unroll
            for (int j = 0; j < 16; j += 4) {
                float4 r4 = *(const float4*)(yp + j);
                v[j] += r4.x; v[j+1] += r4.y; v[j+2] += r4.z; v[j+3] += r4.w;
            }
        }
        float s = 0.f, s2 = 0.f;
#pragma unroll
        for (int j = 0; j < 16; ++j) { s += v[j]; s2 += v[j] * v[j]; }
        s  += __shfl_xor(s, 1);  s  += __shfl_xor(s, 2);  s  += __shfl_xor(s, 4);
        s2 += __shfl_xor(s2, 1); s2 += __shfl_xor(s2, 2); s2 += __shfl_xor(s2, 4);
        float mu  = s * (1.f / HID);
        float var = s2 * (1.f / HID) - mu * mu;
        float inv = rsqrtf(var + 1e-5f);
        unsigned short hi[16], lo[16];
#pragma unroll
        for (int j = 0; j < 16; ++j) {
            int c = cb + j;
            float o = (v[j] - mu) * inv * g[c] + b[c];
            hi[j] = f2b(o); lo[j] = f2b(o - us2f(hi[j]));
        }
        *(uint4*)&sAh[row * 136 + cb]     = *(uint4*)&hi[0];
        *(uint4*)&sAh[row * 136 + cb + 8] = *(uint4*)&hi[8];
        *(uint4*)&sAl[row * 136 + cb]     = *(uint4*)&lo[0];
        *(uint4*)&sAl[row * 136 + cb + 8] = *(uint4*)&lo[8];
    }
    __syncthreads();

    int w = t >> 6, lane = t & 63;
    int m = lane & 15, quad = lane >> 4;
    f32x4 acc[4];
#pragma unroll
    for (int i = 0; i < 4; ++i) acc[i] = (f32x4){0.f, 0.f, 0.f, 0.f};
#pragma unroll
    for (int c = 0; c < 4; ++c) {
        bf16x8 ah = *(const bf16x8*)&sAh[(w * 16 + m) * 136 + c * 32 + quad * 8];
        bf16x8 al = *(const bf16x8*)&sAl[(w * 16 + m) * 136 + c * 32 + quad * 8];
#pragma unroll
        for (int nt = 0; nt < 4; ++nt) {
            bf16x8 wh = *(const bf16x8*)&sWh[(nt * 16 + m) * 136 + c * 32 + quad * 8];
            bf16x8 wl = *(const bf16x8*)&sWl[(nt * 16 + m) * 136 + c * 32 + quad * 8];
            acc[nt] = __builtin_amdgcn_mfma_f32_16x16x32_bf16(ah, wh, acc[nt], 0, 0, 0);
            acc[nt] = __builtin_amdgcn_mfma_f32_16x16x32_bf16(ah, wl, acc[nt], 0, 0, 0);
            acc[nt] = __builtin_amdgcn_mfma_f32_16x16x32_bf16(al, wh, acc[nt], 0, 0, 0);
        }
    }
#pragma unroll
    for (int nt = 0; nt < 4; ++nt) {
#pragma unroll
        for (int r = 0; r < 4; ++r) {
            int row = row0 + w * 16 + quad * 4 + r;
            int col = col0 + nt * 16 + m;
            float v = acc[nt][r];
            if (mode == 0) {
                Cf[(long)row * Nc + col] = v;
            } else {
                v = fmaxf(v, 0.f);
                unsigned short hh = f2b(v);
                Ch[(long)row * Nc + col] = hh;
                Cl[(long)row * Nc + col] = f2b(v - us2f(hh));
            }
        }
    }
}

// ---------- W2 GEMM + residual (+ fused decode on last layer): 16 rows x 128 cols/block.
__global__ __launch_bounds__(256, 3) void k_w2ln(
    const unsigned short* __restrict__ Ah, const unsigned short* __restrict__ Al,   // [4096][512]
    const unsigned short* __restrict__ WH, const unsigned short* __restrict__ WL,   // [128][512]
    const float* __restrict__ yres, float* __restrict__ hout,
    const float* __restrict__ Wdec, float* __restrict__ out)
{
    __shared__ unsigned short sA[2][16 * 72];
    __shared__ unsigned short sW[2][128 * 72];
    int t = threadIdx.x;
    int row0 = blockIdx.x * 16;
    int w = t >> 6, lane = t & 63;
    int m = lane & 15, quad = lane >> 4;
    f32x4 acc[2];
    acc[0] = (f32x4){0.f,0.f,0.f,0.f}; acc[1] = (f32x4){0.f,0.f,0.f,0.f};

    for (int ks = 0; ks < 512; ks += 64) {
        if (ks) __syncthreads();
        {
            int pl = t >> 7, tt = t & 127;
            int r = tt >> 3, ck = tt & 7;
            const unsigned short* src = pl ? Al : Ah;
            *(uint4*)&sA[pl][r * 72 + ck * 8] = *(const uint4*)&src[(long)(row0 + r) * 512 + ks + ck * 8];
        }
        {
            int r0 = t >> 3, ck = t & 7;
#pragma unroll
            for (int p = 0; p < 4; ++p) {
                int n = r0 + p * 32;
                *(uint4*)&sW[0][n * 72 + ck * 8] = *(const uint4*)&WH[(long)n * 512 + ks + ck * 8];
                *(uint4*)&sW[1][n * 72 + ck * 8] = *(const uint4*)&WL[(long)n * 512 + ks + ck * 8];
            }
        }
        __syncthreads();
#pragma unroll
        for (int c = 0; c < 2; ++c) {
            bf16x8 ah = *(const bf16x8*)&sA[0][m * 72 + c * 32 + quad * 8];
            bf16x8 al = *(const bf16x8*)&sA[1][m * 72 + c * 32 + quad * 8];
#pragma unroll
            for (int nt = 0; nt < 2; ++nt) {
                int n = w * 32 + nt * 16 + m;
                bf16x8 wh = *(const bf16x8*)&sW[0][n * 72 + c * 32 + quad * 8];
                bf16x8 wl = *(const bf16x8*)&sW[1][n * 72 + c * 32 + quad * 8];
                acc[nt] = __builtin_amdgcn_mfma_f32_16x16x32_bf16(ah, wh, acc[nt], 0, 0, 0);
                acc[nt] = __builtin_amdgcn_mfma_f32_16x16x32_bf16(ah, wl, acc[nt], 0, 0, 0);
                acc[nt] = __builtin_amdgcn_mfma_f32_16x16x32_bf16(al, wh, acc[nt], 0, 0, 0);
            }
        }
    }
    __syncthreads();                    // all sW reads done; reuse as fp32 tile
    float* ht = (float*)&sW[0][0];      // [16][132]
#pragma unroll
    for (int nt = 0; nt < 2; ++nt) {
#pragma unroll
        for (int r = 0; r < 4; ++r) {
            int row = quad * 4 + r;
            int col = w * 32 + nt * 16 + m;
            float v = acc[nt][r] + yres[(long)(row0 + row) * HID + col];
            hout[(long)(row0 + row) * HID + col] = v;
            ht[row * 132 + col] = v;
        }
    }
    __syncthreads();
    if (Wdec) {                         // fused decode: out = 10*tanh((h@Wdec)/sqrt(128))
        int row = t >> 4, sub = t & 15;
        float v[8];
        *(float4*)&v[0] = *(const float4*)&ht[row * 132 + sub * 8];
        *(float4*)&v[4] = *(const float4*)&ht[row * 132 + sub * 8 + 4];
        float a = 0.f;
#pragma unroll
        for (int j = 0; j < 8; ++j) a += v[j] * Wdec[sub * 8 + j];
        a += __shfl_xor(a, 1); a += __shfl_xor(a, 2); a += __shfl_xor(a, 4); a += __shfl_xor(a, 8);
        if (sub == 0) out[row0 + row] = 10.f * tanhf(a * 0.08838834764831845f);
    }
}

// ---------- attention: grid 512 = b x head x quarter; 4 waves x 16 q-rows.
// QK^T + softmax in fp32 VALU (Ks in LDS); PV via MFMA: P -> per-wave bf16 A-plane,
// V -> transposed bf16 hi/lo B-planes. Defensive barrier before PV.
#define PAS (NS + 8)
__global__ __launch_bounds__(256) void k_attn(const float* __restrict__ qkv,
                                              const float* __restrict__ ef,
                                              const float* __restrict__ sbuf,
                                              int layer,
                                              float* __restrict__ y) {
    __shared__ float Ks[NS][20];                     // 20.5 KB
    __shared__ unsigned short Vh[16][PAS];           // [d][key]
    __shared__ unsigned short Vl[16][PAS];
    __shared__ unsigned short Pa[4][16][PAS];        // per-wave [qrow][key]
    int bid = blockIdx.x;
    int q4 = bid & 3, hh = (bid >> 2) & 7, bb = bid >> 5;
    int t = threadIdx.x;
    {   // stage K fp32 + V bf16 hi/lo transposed
        const float* kr = qkv + ((long)(bb * NS + t)) * 384 + HID + hh * 16;
        *(float4*)&Ks[t][0]  = *(const float4*)kr;
        *(float4*)&Ks[t][4]  = *(const float4*)(kr + 4);
        *(float4*)&Ks[t][8]  = *(const float4*)(kr + 8);
        *(float4*)&Ks[t][12] = *(const float4*)(kr + 12);
        const float* vr = kr + HID;
        float vv[16];
        *(float4*)&vv[0]  = *(const float4*)vr;
        *(float4*)&vv[4]  = *(const float4*)(vr + 4);
        *(float4*)&vv[8]  = *(const float4*)(vr + 8);
        *(float4*)&vv[12] = *(const float4*)(vr + 12);
#pragma unroll
        for (int d = 0; d < 16; ++d) {
            unsigned short hi = f2b(vv[d]);
            Vh[d][t] = hi;
            Vl[d][t] = f2b(vv[d] - us2f(hi));
        }
    }
    __syncthreads();
    int w = t >> 6, lane = t & 63;
    float s1  = sbuf[layer * 16 + hh];
    float s2g = sbuf[layer * 16 + NHEAD + hh];
    int m = lane & 15, quad = lane >> 4;
    unsigned short* Paw = &Pa[w][0][0];
    for (int it = 0; it < 4; ++it) {
        int r0 = q4 * 64 + w * 16 + it * 4;
        float q[4][16];
#pragma unroll
        for (int rr = 0; rr < 4; ++rr) {
            const float* qr = qkv + ((long)(bb * NS + r0 + rr)) * 384 + hh * 16;
            *(float4*)&q[rr][0]  = *(const float4*)qr;
            *(float4*)&q[rr][4]  = *(const float4*)(qr + 4);
            *(float4*)&q[rr][8]  = *(const float4*)(qr + 8);
            *(float4*)&q[rr][12] = *(const float4*)(qr + 12);
        }
        float sc[4][4];
#pragma unroll
        for (int i = 0; i < 4; ++i) {
            int c = i * 64 + lane;
            float kk[16];
            *(float4*)&kk[0]  = *(const float4*)&Ks[c][0];
            *(float4*)&kk[4]  = *(const float4*)&Ks[c][4];
            *(float4*)&kk[8]  = *(const float4*)&Ks[c][8];
            *(float4*)&kk[12] = *(const float4*)&Ks[c][12];
#pragma unroll
            for (int rr = 0; rr < 4; ++rr) {
                float d0 = 0.f;
#pragma unroll
                for (int d = 0; d < 16; ++d) d0 += q[rr][d] * kk[d];
                sc[rr][i] = d0;
            }
        }
#pragma unroll
        for (int rr = 0; rr < 4; ++rr) {
            long eb = ((long)(bb * NS + r0 + rr)) * NS;
            float e0 = ef[eb + lane],       e1 = ef[eb + 64 + lane];
            float e2 = ef[eb + 128 + lane], e3 = ef[eb + 192 + lane];
            float x0 = sc[rr][0] * 0.25f + e0 * s1;
            float x1 = sc[rr][1] * 0.25f + e1 * s1;
            float x2 = sc[rr][2] * 0.25f + e2 * s1;
            float x3 = sc[rr][3] * 0.25f + e3 * s1;
            float mm = fmaxf(fmaxf(x0, x1), fmaxf(x2, x3));
#pragma unroll
            for (int o = 32; o; o >>= 1) mm = fmaxf(mm, __shfl_xor(mm, o));
            float p0 = __expf(x0 - mm), p1 = __expf(x1 - mm);
            float p2 = __expf(x2 - mm), p3 = __expf(x3 - mm);
            float sum = p0 + p1 + p2 + p3;
#pragma unroll
            for (int o = 32; o; o >>= 1) sum += __shfl_xor(sum, o);
            float inv = s2g / sum;
            int prow = it * 4 + rr;     // q-row within this wave's 16-row strip
            Paw[prow * PAS + lane]       = f2b(p0 * inv * e0);
            Paw[prow * PAS + 64 + lane]  = f2b(p1 * inv * e1);
            Paw[prow * PAS + 128 + lane] = f2b(p2 * inv * e2);
            Paw[prow * PAS + 192 + lane] = f2b(p3 * inv * e3);
        }
    }
    __syncthreads();   // defensive: guarantee all Pa writes visible before PV MFMA reads
    // PV via MFMA
    f32x4 acc = (f32x4){0.f, 0.f, 0.f, 0.f};
#pragma unroll
    for (int s = 0; s < 8; ++s) {
        bf16x8 pf = *(const bf16x8*)&Paw[m * PAS + s * 32 + quad * 8];
        bf16x8 vh = *(const bf16x8*)&Vh[m][s * 32 + quad * 8];
        bf16x8 vl = *(const bf16x8*)&Vl[m][s * 32 + quad * 8];
        acc = __builtin_amdgcn_mfma_f32_16x16x32_bf16(pf, vh, acc, 0, 0, 0);
        acc = __builtin_amdgcn_mfma_f32_16x16x32_bf16(pf, vl, acc, 0, 0, 0);
    }
#pragma unroll
    for (int r = 0; r < 4; ++r) {
        int row = q4 * 64 + w * 16 + quad * 4 + r;
        y[((long)(bb * NS + row)) * HID + hh * 16 + m] = acc[r];
    }
}

extern "C" void kernel_launch(void* const* d_in, const int* in_sizes, int n_in,
                              void* d_out, int out_size, void* d_ws, size_t ws_size,
                              hipStream_t stream) {
    const float* nf    = (const float*)d_in[0];
    const float* ef    = (const float*)d_in[1];
    const float* Wn    = (const float*)d_in[2];
    const float* We_in = (const float*)d_in[3];
    const float* ln1g  = (const float*)d_in[4];
    const float* ln1b  = (const float*)d_in[5];
    const float* Wh    = (const float*)d_in[6];
    const float* We    = (const float*)d_in[7];
    const float* ln2g  = (const float*)d_in[8];
    const float* ln2b  = (const float*)d_in[9];
    const float* W1    = (const float*)d_in[10];
    const float* W2    = (const float*)d_in[11];
    const float* Wdec  = (const float*)d_in[12];

    float* ws   = (float*)d_ws;
    float* sbuf = ws;                            // 64 slots
    float* h    = ws + 64;                       // 4096*128
    float* y    = h + ROWS * HID;                // 4096*128
    float* qkv  = y + ROWS * HID;                // 4096*384
    unsigned short* hidH = (unsigned short*)(qkv + (long)ROWS * 384);   // 4096*512
    unsigned short* hidL = hidH + (long)ROWS * 512;
    unsigned short* WhH  = hidL + (long)ROWS * 512;          // 3*384*128
    unsigned short* WhL  = WhH + (long)NL * 384 * 128;
    unsigned short* W1H  = WhL + (long)NL * 384 * 128;       // 3*512*128
    unsigned short* W1L  = W1H + (long)NL * 512 * 128;
    unsigned short* W2H  = W1L + (long)NL * 512 * 128;       // 3*128*512
    unsigned short* W2L  = W2H + (long)NL * 128 * 512;

    k_prep<<<529 + ROWS * HID / 256, 256, 0, stream>>>(Wh, W1, W2, We_in, We, nf, Wn,
                                    WhH, WhL, W1H, W1L, W2H, W2L, sbuf, h);
    for (int l = 0; l < NL; ++l) {
        // LN1 + QKV GEMM
        k_fgemm<<<dim3(6, 64), 256, 0, stream>>>(h, nullptr,
            ln1g + l * HID, ln1b + l * HID,
            WhH + (long)l * 384 * 128, WhL + (long)l * 384 * 128,
            qkv, nullptr, nullptr, 384, 0);
        k_attn<<<512, 256, 0, stream>>>(qkv, ef, sbuf, l, y);
        // LN2(y+h) + W1 GEMM + relu -> planes
        k_fgemm<<<dim3(8, 64), 256, 0, stream>>>(y, h,
            ln2g + l * HID, ln2b + l * HID,
            W1H + (long)l * 512 * 128, W1L + (long)l * 512 * 128,
            nullptr, hidH, hidL, 512, 1);
        // W2 GEMM + residual -> h (+ decode on last layer)
        int last = (l == NL - 1);
        k_w2ln<<<ROWS / 16, 256, 0, stream>>>(hidH, hidL,
            W2H + (long)l * 128 * 512, W2L + (long)l * 128 * 512,
            y, h, last ? Wdec : nullptr, (float*)d_out);
    }
}